// Round 13
// baseline (1958.030 us; speedup 1.0000x reference)
//
#include <hip/hip_runtime.h>

// ---------------- problem constants ----------------
#define TPB   256
#define NWG   512
#define SEQL  200
#define BATCH 64
#define EDIM  300
#define HDIM  512
#define ODIM  5
#define NROW  (4*HDIM)   // 2048 gate rows

// ---------------- group decomposition ----------------
#define GROUPS 16     // independent batch groups (group = blockIdx & 15)
#define GCUS   32     // blocks per group (j = blockIdx >> 4)
#define GB     4      // batch rows per group
#define UNITS  16     // h units per block

// ---------------- persist-kernel LDS layout (word offsets) ----------------
// [0..2048)     h tile [512 k][4 b]; phys = 4k ^ (((k>>5)&3)<<2)
//               wave w writes+reads ONLY rows [128w,128w+128) -> wave-private
// [2048..4096)  ex[2 par][4 w][4 g][4 b][16 u]  (parity double-buffer)
// [4096..5296)  embT[300][4] (fallback only)
#define EX_OFF   2048
#define EMB_OFF  4096
#define LDS_BYTES 56320                      // 55 KiB: 2 blocks/CU fit, 3 don't

// ---------------- tagged h exchange ----------------
// htag[parity][group][2048] : ull = (tag << 32) | f32bits(value)
// value index vi = k*4 + b. Input for step s: parity s&1, tag == s.
#define HT_GROUP 2048
#define HT_PAR   (GROUPS * HT_GROUP)               // 32768 ull per parity
#define HT_BYTES (2 * HT_PAR * 8)                  // 512 KiB

// ---------------- precompute-kernel LDS ----------------
#define ESTR 308
#define PRE_LDS_BYTES (BATCH * ESTR * 4)     // 78848 B

#define GATES_FLOATS ((size_t)SEQL * NROW * BATCH)   // 104.9 MB

__device__ __forceinline__ float fast_sigmoid(float x) {
    return 1.0f / (1.0f + __expf(-x));
}
__device__ __forceinline__ float fast_tanh(float x) {
    return 2.0f / (1.0f + __expf(-2.0f * x)) - 1.0f;
}

// ============================================================================
// Precompute: gates[s][group][gate-row][4] for batch 4g..4g+3 (group-major).
// ============================================================================
extern "C" __global__ void __launch_bounds__(256, 1)
lstm_pre(const int* __restrict__ x, const float* __restrict__ emb,
         const float* __restrict__ W_ih, float* __restrict__ gates)
{
    extern __shared__ float embs[];
    const int tid = threadIdx.x;
    const int s   = blockIdx.x >> 3;
    const int rb  = blockIdx.x & 7;

    for (int i = tid; i < BATCH * 75; i += 256) {
        int b = i / 75, jj = i - b * 75;
        int row = x[b * SEQL + s];
        float4 v = ((const float4*)(emb + (size_t)row * EDIM))[jj];
        *(float4*)&embs[b * ESTR + 4 * jj] = v;
    }
    __syncthreads();

    const int bi = tid >> 5;      // batch octet (groups 2bi, 2bi+1)
    const int ri = tid & 31;
    const int row0 = rb * 256 + ri * 8;
    const float* wp = W_ih + (size_t)row0 * EDIM;

    float acc[8][8];
#pragma unroll
    for (int a = 0; a < 8; a++)
#pragma unroll
        for (int b = 0; b < 8; b++) acc[a][b] = 0.0f;

    for (int t2 = 0; t2 < 75; t2++) {
        float4 w[8], e[8];
#pragma unroll
        for (int rr = 0; rr < 8; rr++)
            w[rr] = *(const float4*)(wp + rr * EDIM + 4 * t2);
#pragma unroll
        for (int bb = 0; bb < 8; bb++)
            e[bb] = *(const float4*)&embs[(bi * 8 + bb) * ESTR + 4 * t2];
#pragma unroll
        for (int rr = 0; rr < 8; rr++)
#pragma unroll
            for (int bb = 0; bb < 8; bb++) {
                acc[rr][bb] = fmaf(w[rr].x, e[bb].x, acc[rr][bb]);
                acc[rr][bb] = fmaf(w[rr].y, e[bb].y, acc[rr][bb]);
                acc[rr][bb] = fmaf(w[rr].z, e[bb].z, acc[rr][bb]);
                acc[rr][bb] = fmaf(w[rr].w, e[bb].w, acc[rr][bb]);
            }
    }
    float* dstA = gates + (size_t)(s * GROUPS + 2 * bi)     * 8192 + row0 * 4;
    float* dstB = gates + (size_t)(s * GROUPS + 2 * bi + 1) * 8192 + row0 * 4;
#pragma unroll
    for (int rr = 0; rr < 8; rr++) {
        *(float4*)(dstA + 4 * rr) = make_float4(acc[rr][0], acc[rr][1], acc[rr][2], acc[rr][3]);
        *(float4*)(dstB + 4 * rr) = make_float4(acc[rr][4], acc[rr][5], acc[rr][6], acc[rr][7]);
    }
}

// ============================================================================
// Persistent LSTM, 16 groups x 32 blocks, 2 blocks/CU. ONE barrier per step:
// wave w owns k-quarter [128w,128w+128); lane (u=l>>2, kq=l&3) holds ALL 4
// gates of unit u over a 32-k slice -> k-reduce = 2 shfl_xor rounds (no LDS);
// cross-wave combine via parity-double-buffered ex + one __syncthreads; cell
// split symmetrically across waves (units 4w..4w+3 per wave).
// ============================================================================
extern "C" __global__ void __launch_bounds__(TPB, 2)
lstm_persist(const int* __restrict__ x, const float* __restrict__ emb,
             const float* __restrict__ W_ih, const float* __restrict__ W_hh,
             const float* __restrict__ b_ih, const float* __restrict__ b_hh,
             const float* __restrict__ gates,      // may be null
             unsigned long long* __restrict__ htag) // [2][16][2048] tagged h
{
    extern __shared__ float lds[];
    const int tid = threadIdx.x;
    const int g   = blockIdx.x & 15;
    const int j   = blockIdx.x >> 4;        // 0..31
    const bool pre = (gates != nullptr);

    const int wv = tid >> 6;      // wave 0..3 (k-quarter)
    const int l  = tid & 63;      // lane
    const int u  = l >> 2;        // unit 0..15
    const int kq = l & 3;         // 32-k subslice within quarter
    const int kbase = 128 * wv + 32 * kq;

    // ---- W_hh: 4 gates x unit u x 32 k -> 128 VGPRs (static idx, rule #20) ----
    float4 w4[4][8];
#pragma unroll
    for (int p = 0; p < 4; p++) {            // p = gate
        const size_t R = (size_t)(p * HDIM + UNITS * j + u);
        const float* wp = W_hh + R * HDIM + kbase;
#pragma unroll
        for (int q = 0; q < 8; q++) w4[p][q] = *(const float4*)(wp + 4 * q);
    }
#pragma unroll
    for (int p = 0; p < 4; p++)
#pragma unroll
        for (int q = 0; q < 8; q++)
            asm volatile("" : "+v"(w4[p][q].x), "+v"(w4[p][q].y),
                             "+v"(w4[p][q].z), "+v"(w4[p][q].w));

    // cell role: lanes l<16 of wave wv own (cu = 4wv + (l>>2), cb = l&3)
    const int cu = 4 * wv + ((l >> 2) & 3);
    const int cb = l & 3;
    float bias4[4];
#pragma unroll
    for (int gt = 0; gt < 4; gt++) {
        int R = gt * HDIM + UNITS * j + cu;
        bias4[gt] = b_ih[R] + b_hh[R];
    }
    float c_reg = 0.0f;

    unsigned long long* const T0 = htag + (size_t)g * HT_GROUP;            // parity 0
    unsigned long long* const T1 = htag + HT_PAR + (size_t)g * HT_GROUP;   // parity 1

    __syncthreads();

    for (int s = 0; s < SEQL; s++) {
        const unsigned long long* Tin = (s & 1) ? T1 : T0;
        unsigned long long*       Tout = (s & 1) ? T0 : T1;
        const int par = s & 1;

        // ---- (0) prefetch input-proj gates (cell lanes; used after barrier) ----
        float gp[4] = {0.f, 0.f, 0.f, 0.f};
        if (pre && l < 16) {
            const float* gbase = gates + (size_t)(s * GROUPS + g) * 8192;
#pragma unroll
            for (int gt = 0; gt < 4; gt++)
                gp[gt] = __builtin_nontemporal_load(gbase + gt * 2048 + 64 * j + 4 * cu + cb);
        }

        float acc[4][4];                       // [gate][b]
#pragma unroll
        for (int p = 0; p < 4; p++)
#pragma unroll
            for (int b = 0; b < 4; b++) acc[p][b] = 0.f;

        // ---- (1) fallback pass A (cold path; pre-path skips) ----
        if (!pre) {
            for (int i = tid; i < EDIM * GB; i += TPB) {
                int e = i >> 2, b = i & 3;
                int row = x[(GB * g + b) * SEQL + s];
                lds[EMB_OFF + i] = emb[(size_t)row * EDIM + e];
            }
            __syncthreads();
            const int sl = 4 * wv + kq;        // e-slice 0..15
            const int e0 = 19 * sl, e1 = (19 * sl + 19 < EDIM) ? 19 * sl + 19 : EDIM;
            for (int e = e0; e < e1; e++) {
                float4 ev = *(const float4*)&lds[EMB_OFF + 4 * e];
#pragma unroll
                for (int p = 0; p < 4; p++) {
                    float wc = W_ih[(size_t)(p * HDIM + UNITS * j + u) * EDIM + e];
                    acc[p][0] = fmaf(wc, ev.x, acc[p][0]);
                    acc[p][1] = fmaf(wc, ev.y, acc[p][1]);
                    acc[p][2] = fmaf(wc, ev.z, acc[p][2]);
                    acc[p][3] = fmaf(wc, ev.w, acc[p][3]);
                }
            }
            __syncthreads();   // all readers done before next step's staging
        }

        // ---- (2) WAVE-LOCAL poll+stage: lane stages k = 128wv + 2l + rr ----
        {
            const unsigned tag = (unsigned)s;
#pragma unroll
            for (int rr = 0; rr < 2; rr++) {
                const int k = 128 * wv + 2 * l + rr;
                const int vi = 4 * k;
                unsigned long long d0, d1, d2, d3;
                for (;;) {
                    d0 = __hip_atomic_load(Tin + vi + 0, __ATOMIC_RELAXED, __HIP_MEMORY_SCOPE_AGENT);
                    d1 = __hip_atomic_load(Tin + vi + 1, __ATOMIC_RELAXED, __HIP_MEMORY_SCOPE_AGENT);
                    d2 = __hip_atomic_load(Tin + vi + 2, __ATOMIC_RELAXED, __HIP_MEMORY_SCOPE_AGENT);
                    d3 = __hip_atomic_load(Tin + vi + 3, __ATOMIC_RELAXED, __HIP_MEMORY_SCOPE_AGENT);
                    if ((unsigned)(d0 >> 32) == tag && (unsigned)(d1 >> 32) == tag &&
                        (unsigned)(d2 >> 32) == tag && (unsigned)(d3 >> 32) == tag)
                        break;
                    __builtin_amdgcn_s_sleep(1);
                }
                const int phys = (4 * k) ^ (((k >> 5) & 3) << 2);
                float4 hv;
                hv.x = __uint_as_float((unsigned)d0);
                hv.y = __uint_as_float((unsigned)d1);
                hv.z = __uint_as_float((unsigned)d2);
                hv.w = __uint_as_float((unsigned)d3);
                *(float4*)&lds[phys] = hv;
            }
        }
        // wave-local RAW through LDS (in-order DS pipe); stop compiler reorder
        asm volatile("" ::: "memory");
        __builtin_amdgcn_sched_barrier(0);

        // ---- (3) pass B: W_hh regs x own k-slice (reads conflict-free) ----
#pragma unroll
        for (int q = 0; q < 8; q++) {
#pragma unroll
            for (int ki = 0; ki < 4; ki++) {
                const int k = kbase + 4 * q + ki;
                const float4 h0 = *(const float4*)&lds[(4 * k) ^ (kq << 2)];
#pragma unroll
                for (int p = 0; p < 4; p++) {
                    const float4 wvv = w4[p][q];
                    const float wc = ki == 0 ? wvv.x : ki == 1 ? wvv.y
                                   : ki == 2 ? wvv.z : wvv.w;
                    acc[p][0] = fmaf(wc, h0.x, acc[p][0]);
                    acc[p][1] = fmaf(wc, h0.y, acc[p][1]);
                    acc[p][2] = fmaf(wc, h0.z, acc[p][2]);
                    acc[p][3] = fmaf(wc, h0.w, acc[p][3]);
                }
            }
        }

        // ---- (4) k-reduce over kq lanes: 2 shfl_xor rounds (no LDS) ----
#pragma unroll
        for (int p = 0; p < 4; p++)
#pragma unroll
            for (int b = 0; b < 4; b++) {
                acc[p][b] += __shfl_xor(acc[p][b], 1);
                acc[p][b] += __shfl_xor(acc[p][b], 2);
            }

        // ---- (5) ex-write (kq==0 lanes): ex[par][wv][g][b][u], word-scatter ----
        if (kq == 0) {
            const int base = EX_OFF + par * 1024 + wv * 256 + u;
#pragma unroll
            for (int p = 0; p < 4; p++)
#pragma unroll
                for (int b = 0; b < 4; b++)
                    lds[base + p * 64 + b * 16] = acc[p][b];
        }
        __syncthreads();   // the ONLY barrier: ex visible to all cell lanes

        // ---- (6) cell update + tagged store (lanes l<16, units 4wv..4wv+3) ----
        if (l < 16) {
            float gs[4];
#pragma unroll
            for (int gt = 0; gt < 4; gt++) {
                const int base = EX_OFF + par * 1024 + gt * 64 + cb * 16 + cu;
                gs[gt] = bias4[gt] + gp[gt]
                       + lds[base] + lds[base + 256] + lds[base + 512] + lds[base + 768];
            }
            float iv = fast_sigmoid(gs[0]);
            float fv = fast_sigmoid(gs[1]);
            float gv = fast_tanh(gs[2]);
            float ov = fast_sigmoid(gs[3]);
            c_reg = fv * c_reg + iv * gv;
            float hv = ov * fast_tanh(c_reg);
            unsigned long long wword =
                ((unsigned long long)(unsigned)(s + 1) << 32) |
                (unsigned long long)__float_as_uint(hv);
            __hip_atomic_store(Tout + 64 * j + 4 * cu + cb, wword,
                               __ATOMIC_RELAXED, __HIP_MEMORY_SCOPE_AGENT);
        }
        // no second barrier: ex is parity-buffered; any wave's ex-write(s+2)
        // is behind its barrier(s+1), which is behind every wave's cell-read(s).
    }
}

// FC head + softmax. Final h: parity 0 (s=199 stores to T0); value = lo32.
extern "C" __global__ void __launch_bounds__(320)
lstm_epilogue(const unsigned long long* __restrict__ htag,
              const float* __restrict__ W_fc, const float* __restrict__ b_fc,
              float* __restrict__ out)
{
    __shared__ float sl[ODIM * BATCH];
    const int t = threadIdx.x;
    {
        int o = t / BATCH, b = t - o * BATCH;
        const unsigned long long* hb = htag + (size_t)(b >> 2) * HT_GROUP;
        const int bc = b & 3;
        float acc = b_fc[o];
        const float4* wv = (const float4*)(W_fc + o * HDIM);
#pragma unroll 8
        for (int k4 = 0; k4 < HDIM / 4; k4++) {
            float4 w = wv[k4];
            const int k0 = 4 * k4;
            acc = fmaf(__uint_as_float((unsigned)hb[(k0 + 0) * 4 + bc]), w.x, acc);
            acc = fmaf(__uint_as_float((unsigned)hb[(k0 + 1) * 4 + bc]), w.y, acc);
            acc = fmaf(__uint_as_float((unsigned)hb[(k0 + 2) * 4 + bc]), w.z, acc);
            acc = fmaf(__uint_as_float((unsigned)hb[(k0 + 3) * 4 + bc]), w.w, acc);
        }
        sl[o * BATCH + b] = acc;
    }
    __syncthreads();
    if (t < BATCH) {
        float l0 = sl[t], l1 = sl[BATCH + t], l2 = sl[2 * BATCH + t];
        float l3 = sl[3 * BATCH + t], l4 = sl[4 * BATCH + t];
        float m = fmaxf(fmaxf(fmaxf(l0, l1), fmaxf(l2, l3)), l4);
        float e0 = __expf(l0 - m), e1 = __expf(l1 - m), e2 = __expf(l2 - m);
        float e3 = __expf(l3 - m), e4 = __expf(l4 - m);
        float inv = 1.0f / (e0 + e1 + e2 + e3 + e4);
        out[t * ODIM + 0] = e0 * inv;
        out[t * ODIM + 1] = e1 * inv;
        out[t * ODIM + 2] = e2 * inv;
        out[t * ODIM + 3] = e3 * inv;
        out[t * ODIM + 4] = e4 * inv;
    }
}

extern "C" void kernel_launch(void* const* d_in, const int* in_sizes, int n_in,
                              void* d_out, int out_size, void* d_ws, size_t ws_size,
                              hipStream_t stream)
{
    const int*   x    = (const int*)d_in[0];
    const float* emb  = (const float*)d_in[1];
    const float* W_ih = (const float*)d_in[2];
    const float* W_hh = (const float*)d_in[3];
    const float* b_ih = (const float*)d_in[4];
    const float* b_hh = (const float*)d_in[5];
    const float* W_fc = (const float*)d_in[6];
    const float* b_fc = (const float*)d_in[7];
    float* out = (float*)d_out;

    // ws layout: [htag 512 KiB][gates 105 MB (optional)]
    unsigned long long* htag = (unsigned long long*)d_ws;
    const size_t gates_bytes = GATES_FLOATS * sizeof(float);
    float* gates = nullptr;
    if (ws_size >= (size_t)HT_BYTES + gates_bytes)
        gates = (float*)((char*)d_ws + HT_BYTES);

    (void)hipMemsetAsync(htag, 0, HT_BYTES, stream);   // tag 0 / h = 0 for step 0

    (void)hipFuncSetAttribute((const void*)lstm_persist,
                              hipFuncAttributeMaxDynamicSharedMemorySize, LDS_BYTES);
    if (gates) {
        (void)hipFuncSetAttribute((const void*)lstm_pre,
                                  hipFuncAttributeMaxDynamicSharedMemorySize, PRE_LDS_BYTES);
        lstm_pre<<<SEQL * 8, 256, PRE_LDS_BYTES, stream>>>(x, emb, W_ih, gates);
    }

    lstm_persist<<<NWG, TPB, LDS_BYTES, stream>>>(x, emb, W_ih, W_hh, b_ih, b_hh,
                                                  gates, htag);

    lstm_epilogue<<<1, 320, 0, stream>>>(htag, W_fc, b_fc, out);
}